// Round 14
// baseline (274.328 us; speedup 1.0000x reference)
//
#include <hip/hip_runtime.h>
#include <math.h>

#define N_NODES 50000
#define N_EDGES 800000
#define DIM 64
#define SLOT_SHIFT 6         // 64 slots per node (max degree: Poisson(16), P>=64 ~ 1e-20)
#define SC_EPB 1024          // edges per scatter vblock
#define NB_SC 782            // ceil(800000/1024)
#define NB_NL 782            // ceil(50000/64)
#define NB_GAT 3125          // 50000/16
#define K1_GRID 1564         // 1:1 interleave nl|scatter
#define PAD 6                // LDS row pad: 70 ushorts = 35 words -> 2-way max (free)

// ---- bf16 helpers (RNE) ----
__device__ __forceinline__ ushort f2bf(float x) {
    unsigned b = __float_as_uint(x);
    return (ushort)((b + 0x7FFFu + ((b >> 16) & 1u)) >> 16);
}
__device__ __forceinline__ float bf2f(ushort u) {
    return __uint_as_float(((unsigned)u) << 16);
}

// ============================== node GEMM body ==============================
// bf16 LDS staging, +6 pad (35-word rows: lanes at rows 4m hit 8 banks -> 2-way, free).
// zb = bf16(h @ W^T), zib = bf16(h @ U^T), s_src/s_dst = attention projections of z.
template<bool IN_BF16>
__device__ __forceinline__ void nl_body(
    int vb, const void* __restrict__ hin, const float* __restrict__ W,
    const float* __restrict__ U, const float* __restrict__ A,
    ushort* __restrict__ zb, ushort* __restrict__ zib,
    float* __restrict__ s_src, float* __restrict__ s_dst,
    ushort (*Ws)[DIM + PAD], ushort (*Us)[DIM + PAD], ushort (*hs)[DIM + PAD])
{
    const int tid = threadIdx.x;
    const int row0 = vb * 64;

    for (int i = tid; i < 1024; i += 256) {
        int r = i >> 4, c = (i & 15) * 4;
        float4 w4 = ((const float4*)W)[i];
        float4 u4 = ((const float4*)U)[i];
        ushort4 wp, up;
        wp.x = f2bf(w4.x); wp.y = f2bf(w4.y); wp.z = f2bf(w4.z); wp.w = f2bf(w4.w);
        up.x = f2bf(u4.x); up.y = f2bf(u4.y); up.z = f2bf(u4.z); up.w = f2bf(u4.w);
        *(ushort4*)&Ws[r][c] = wp;
        *(ushort4*)&Us[r][c] = up;
        int n = row0 + r;
        ushort4 hp; hp.x = hp.y = hp.z = hp.w = 0;
        if (n < N_NODES) {
            if (IN_BF16) {
                hp = ((const ushort4*)hin)[((size_t)n * DIM + c) >> 2];
            } else {
                float4 h4 = ((const float4*)hin)[((size_t)n * DIM + c) >> 2];
                hp.x = f2bf(h4.x); hp.y = f2bf(h4.y); hp.z = f2bf(h4.z); hp.w = f2bf(h4.w);
            }
        }
        *(ushort4*)&hs[r][c] = hp;
    }
    __syncthreads();

    const int rb = (tid >> 4) * 4;
    const int cb = (tid & 15) * 4;

    float accz[4][4] = {{0}}, accu[4][4] = {{0}};
    #pragma unroll 4
    for (int k = 0; k < DIM; k += 4) {
        float hv[4][4], wv[4][4], uv[4][4];
        #pragma unroll
        for (int r = 0; r < 4; ++r) {
            ushort4 hb = *(const ushort4*)&hs[rb + r][k];
            hv[r][0] = bf2f(hb.x); hv[r][1] = bf2f(hb.y);
            hv[r][2] = bf2f(hb.z); hv[r][3] = bf2f(hb.w);
        }
        #pragma unroll
        for (int c = 0; c < 4; ++c) {
            ushort4 wb = *(const ushort4*)&Ws[cb + c][k];
            ushort4 ub = *(const ushort4*)&Us[cb + c][k];
            wv[c][0] = bf2f(wb.x); wv[c][1] = bf2f(wb.y);
            wv[c][2] = bf2f(wb.z); wv[c][3] = bf2f(wb.w);
            uv[c][0] = bf2f(ub.x); uv[c][1] = bf2f(ub.y);
            uv[c][2] = bf2f(ub.z); uv[c][3] = bf2f(ub.w);
        }
        #pragma unroll
        for (int r = 0; r < 4; ++r)
            #pragma unroll
            for (int c = 0; c < 4; ++c) {
                accz[r][c] += hv[r][0] * wv[c][0] + hv[r][1] * wv[c][1]
                            + hv[r][2] * wv[c][2] + hv[r][3] * wv[c][3];
                accu[r][c] += hv[r][0] * uv[c][0] + hv[r][1] * uv[c][1]
                            + hv[r][2] * uv[c][2] + hv[r][3] * uv[c][3];
            }
    }

    float asrc[4], adst[4];
    #pragma unroll
    for (int c = 0; c < 4; ++c) { asrc[c] = A[cb + c]; adst[c] = A[DIM + cb + c]; }

    float ps[4], pd[4];
    #pragma unroll
    for (int r = 0; r < 4; ++r) {
        int n = row0 + rb + r;
        if (n < N_NODES) {
            ushort4 vz, vu;
            vz.x = f2bf(accz[r][0]); vz.y = f2bf(accz[r][1]);
            vz.z = f2bf(accz[r][2]); vz.w = f2bf(accz[r][3]);
            vu.x = f2bf(accu[r][0]); vu.y = f2bf(accu[r][1]);
            vu.z = f2bf(accu[r][2]); vu.w = f2bf(accu[r][3]);
            *(ushort4*)&zb[(size_t)n * DIM + cb]  = vz;
            *(ushort4*)&zib[(size_t)n * DIM + cb] = vu;
        }
        float s = 0.f, t = 0.f;
        #pragma unroll
        for (int c = 0; c < 4; ++c) { s += accz[r][c] * asrc[c]; t += accz[r][c] * adst[c]; }
        ps[r] = s; pd[r] = t;
    }
    #pragma unroll
    for (int m = 1; m < 16; m <<= 1) {
        #pragma unroll
        for (int r = 0; r < 4; ++r) {
            ps[r] += __shfl_xor(ps[r], m, 64);
            pd[r] += __shfl_xor(pd[r], m, 64);
        }
    }
    if ((tid & 15) == 0) {
        #pragma unroll
        for (int r = 0; r < 4; ++r) {
            int n = row0 + rb + r;
            if (n < N_NODES) { s_src[n] = ps[r]; s_dst[n] = pd[r]; }
        }
    }
}

// ============================== scatter body ==============================
// Direct-to-node-slot scatter: edata[(d<<6) + atomicAdd(deg[d],1)] = (src<<16)|bf16(dval).
// Eliminates bucket_sort entirely. deg = 200 KB, L2-resident, 16 RMW/counter.
__device__ __forceinline__ void scatter_body(
    int vb, const int* __restrict__ src, const int* __restrict__ dst,
    const float* __restrict__ dfeat, int* __restrict__ deg,
    unsigned* __restrict__ edata)
{
    int base = vb * SC_EPB;
    #pragma unroll
    for (int j = 0; j < SC_EPB / 256; ++j) {
        int e = base + j * 256 + threadIdx.x;
        if (e < N_EDGES) {
            int d = dst[e];
            int slot = atomicAdd(&deg[d], 1);
            edata[((size_t)d << SLOT_SHIFT) + slot] =
                ((unsigned)src[e] << 16) | (unsigned)f2bf(dfeat[e]);
        }
    }
}

// ============================== K1: nl1 || scatter, 1:1 interleave ==============================
struct K1NL { ushort Ws[DIM][DIM + PAD]; ushort Us[DIM][DIM + PAD]; ushort hs[64][DIM + PAD]; };

__global__ __launch_bounds__(256) void k1_nl_part(
    const float* __restrict__ h, const float* __restrict__ W0,
    const float* __restrict__ U0, const float* __restrict__ A0,
    ushort* __restrict__ zb, ushort* __restrict__ zib,
    float* __restrict__ ssrc, float* __restrict__ sdst,
    const int* __restrict__ src, const int* __restrict__ dst,
    const float* __restrict__ dd, int* __restrict__ deg, unsigned* __restrict__ edata)
{
    __shared__ K1NL sm;
    int bid = blockIdx.x;
    if (bid & 1)
        scatter_body(bid >> 1, src, dst, dd, deg, edata);
    else
        nl_body<false>(bid >> 1, h, W0, U0, A0, zb, zib, ssrc, sdst,
                       sm.Ws, sm.Us, sm.hs);
}

// standalone layer-2 GEMM
__global__ __launch_bounds__(256) void node_linear2(
    const ushort* __restrict__ h1b, const float* __restrict__ W,
    const float* __restrict__ U, const float* __restrict__ A,
    ushort* __restrict__ zb, ushort* __restrict__ zib,
    float* __restrict__ ssrc, float* __restrict__ sdst)
{
    __shared__ K1NL sm;
    nl_body<true>(blockIdx.x, h1b, W, U, A, zb, zib, ssrc, sdst, sm.Ws, sm.Us, sm.hs);
}

// ============================== fused GAT ==============================
// GROUP-PER-NODE (16 lanes/node); node's edges at edata[n<<6 .. +deg[n]];
// packed (src<<16|bf16(ex)) single broadcast; 8-deep gather.
template<bool OUT_BF16>
__global__ __launch_bounds__(256) void gat_fused(
    const int* __restrict__ deg, const unsigned* __restrict__ edata,
    const float* __restrict__ s_src, const float* __restrict__ s_dst,
    const ushort* __restrict__ zb, const ushort* __restrict__ zib,
    const float* __restrict__ V, const float* __restrict__ A,
    void* __restrict__ out)
{
    const int n = blockIdx.x * 16 + (threadIdx.x >> 4);   // 50000 = 16*3125, no tail
    const int q = threadIdx.x & 15;
    const int gbase = threadIdx.x & 48;

    int beg = n << SLOT_SHIFT;
    int end = beg + deg[n];
    if (beg == end) {
        if (OUT_BF16) {
            ushort4 zz; zz.x = zz.y = zz.z = zz.w = 0;
            ((ushort4*)out)[(size_t)n * 16 + q] = zz;
        } else {
            ((float4*)out)[(size_t)n * 16 + q] = make_float4(0.f, 0.f, 0.f, 0.f);
        }
        return;
    }

    float vae = V[0] * A[2 * DIM];
    float sd = s_dst[n];

    float l = 0.f;
    float4 a0 = make_float4(0.f, 0.f, 0.f, 0.f);
    float4 a1 = make_float4(0.f, 0.f, 0.f, 0.f);

    for (int c0 = beg; c0 < end; c0 += 16) {
        int c = c0 + q;
        bool valid = c < end;
        unsigned w = valid ? edata[c] : 0u;
        int s = (int)(w >> 16);
        float dv = bf2f((ushort)(w & 0xFFFFu));
        float e = s_src[s] + sd + dv * vae;
        e = (e >= 0.f) ? e : 0.01f * e;
        float ex = valid ? __expf(e) : 0.f;

        float cs = ex;
        #pragma unroll
        for (int off = 8; off >= 1; off >>= 1) cs += __shfl_xor(cs, off, 16);
        l += cs;

        unsigned w2 = valid ? (((unsigned)s << 16) | (unsigned)f2bf(ex)) : 0u;

        int cnt = min(16, end - c0);
        for (int k = 0; k < cnt; k += 8) {
            unsigned wsj[8];
            ushort4 v[8];
            #pragma unroll
            for (int j = 0; j < 8; ++j) {
                wsj[j] = __shfl(w2, gbase + k + j, 64);
                v[j] = *(const ushort4*)&zb[((size_t)(wsj[j] >> 16) << 6) + (q << 2)];
            }
            #pragma unroll
            for (int j = 0; j < 8; ++j) {
                float ej = bf2f((ushort)(wsj[j] & 0xFFFFu));
                if (j & 1) {
                    a1.x += ej * bf2f(v[j].x); a1.y += ej * bf2f(v[j].y);
                    a1.z += ej * bf2f(v[j].z); a1.w += ej * bf2f(v[j].w);
                } else {
                    a0.x += ej * bf2f(v[j].x); a0.y += ej * bf2f(v[j].y);
                    a0.z += ej * bf2f(v[j].z); a0.w += ej * bf2f(v[j].w);
                }
            }
        }
    }
    float inv = 1.f / l;
    ushort4 zu = ((const ushort4*)zib)[(size_t)n * 16 + q];
    float4 o;
    o.x = fmaxf(bf2f(zu.x) + (a0.x + a1.x) * inv, 0.f);
    o.y = fmaxf(bf2f(zu.y) + (a0.y + a1.y) * inv, 0.f);
    o.z = fmaxf(bf2f(zu.z) + (a0.z + a1.z) * inv, 0.f);
    o.w = fmaxf(bf2f(zu.w) + (a0.w + a1.w) * inv, 0.f);
    if (OUT_BF16) {
        ushort4 ob;
        ob.x = f2bf(o.x); ob.y = f2bf(o.y); ob.z = f2bf(o.z); ob.w = f2bf(o.w);
        ((ushort4*)out)[(size_t)n * 16 + q] = ob;
    } else {
        ((float4*)out)[(size_t)n * 16 + q] = o;
    }
}

// ============================== driver ==============================
extern "C" void kernel_launch(void* const* d_in, const int* in_sizes, int n_in,
                              void* d_out, int out_size, void* d_ws, size_t ws_size,
                              hipStream_t stream)
{
    const float* h  = (const float*)d_in[0];
    const float* dd = (const float*)d_in[1];
    const int* src  = (const int*)d_in[2];
    const int* dst  = (const int*)d_in[3];
    const float* V0 = (const float*)d_in[4];
    const float* W0 = (const float*)d_in[5];
    const float* U0 = (const float*)d_in[6];
    const float* A0 = (const float*)d_in[7];
    const float* V1 = (const float*)d_in[8];
    const float* W1 = (const float*)d_in[9];
    const float* U1 = (const float*)d_in[10];
    const float* A1 = (const float*)d_in[11];

    const size_t ND = (size_t)N_NODES * DIM;   // 3.2M
    float* ws    = (float*)d_ws;
    ushort* zb   = (ushort*)ws;                     // ND ushort
    ushort* zib  = zb + ND;                         // ND ushort
    ushort* h1b  = zib + ND;                        // ND ushort
    float* ssrc  = ws + (3 * ND) / 2;               // N floats
    float* sdst  = ssrc + N_NODES;                  // N floats
    unsigned* edata = (unsigned*)(sdst + N_NODES);  // N*64 u32 (12.8 MB)
    int*   deg   = (int*)(edata + ((size_t)N_NODES << SLOT_SHIFT)); // N int
    float* out   = (float*)d_out;

    // zero per-node degree counters (200 KB), then layer-1 GEMM || direct-slot scatter
    hipMemsetAsync(deg, 0, N_NODES * sizeof(int), stream);
    k1_nl_part<<<K1_GRID, 256, 0, stream>>>(h, W0, U0, A0, zb, zib, ssrc, sdst,
                                            src, dst, dd, deg, edata);
    gat_fused<true><<<NB_GAT, 256, 0, stream>>>(deg, edata, ssrc, sdst, zb, zib, V0, A0, h1b);
    node_linear2<<<NB_NL, 256, 0, stream>>>(h1b, W1, U1, A1, zb, zib, ssrc, sdst);
    gat_fused<false><<<NB_GAT, 256, 0, stream>>>(deg, edata, ssrc, sdst, zb, zib, V1, A1, out);
}

// Round 15
// 195.138 us; speedup vs baseline: 1.4058x; 1.4058x over previous
//
#include <hip/hip_runtime.h>
#include <math.h>

#define N_NODES 50000
#define N_EDGES 800000
#define DIM 64
#define NPB 128
#define NPB_SHIFT 7
#define NBUCKET 391          // ceil(50000/128)
#define CAP 2560             // slot capacity per bucket (mean 2048, sd ~45 -> 11 sigma)
#define EPB 2048             // edges per partition vblock
#define NBLK 391             // ceil(800000/2048)
#define NB_NL 782            // ceil(50000/64)
#define NB_GAT 3125          // 50000/16

// ---- bf16 helpers (RNE) ----
__device__ __forceinline__ ushort f2bf(float x) {
    unsigned b = __float_as_uint(x);
    return (ushort)((b + 0x7FFFu + ((b >> 16) & 1u)) >> 16);
}
__device__ __forceinline__ float bf2f(ushort u) {
    return __uint_as_float(((unsigned)u) << 16);
}

// ============================== node GEMM body ==============================
// fp32 LDS staging, +1 pad (conflict-free). zb = bf16(h @ W^T), zib = bf16(h @ U^T),
// s_src/s_dst = attention projections of z.
template<bool IN_BF16>
__device__ __forceinline__ void nl_body(
    int vb, const void* __restrict__ hin, const float* __restrict__ W,
    const float* __restrict__ U, const float* __restrict__ A,
    ushort* __restrict__ zb, ushort* __restrict__ zib,
    float* __restrict__ s_src, float* __restrict__ s_dst,
    float (*Ws)[DIM + 1], float (*Us)[DIM + 1], float (*hs)[DIM + 1])
{
    const int tid = threadIdx.x;
    const int row0 = vb * 64;

    for (int i = tid; i < 1024; i += 256) {
        int r = i >> 4, c = (i & 15) * 4;
        float4 w4 = ((const float4*)W)[i];
        float4 u4 = ((const float4*)U)[i];
        Ws[r][c] = w4.x; Ws[r][c + 1] = w4.y; Ws[r][c + 2] = w4.z; Ws[r][c + 3] = w4.w;
        Us[r][c] = u4.x; Us[r][c + 1] = u4.y; Us[r][c + 2] = u4.z; Us[r][c + 3] = u4.w;
        int n = row0 + r;
        float4 h4 = make_float4(0.f, 0.f, 0.f, 0.f);
        if (n < N_NODES) {
            if (IN_BF16) {
                ushort4 hb = ((const ushort4*)hin)[((size_t)n * DIM + c) >> 2];
                h4 = make_float4(bf2f(hb.x), bf2f(hb.y), bf2f(hb.z), bf2f(hb.w));
            } else {
                h4 = ((const float4*)hin)[((size_t)n * DIM + c) >> 2];
            }
        }
        hs[r][c] = h4.x; hs[r][c + 1] = h4.y; hs[r][c + 2] = h4.z; hs[r][c + 3] = h4.w;
    }
    __syncthreads();

    const int rb = (tid >> 4) * 4;
    const int cb = (tid & 15) * 4;

    float accz[4][4] = {{0}}, accu[4][4] = {{0}};
    #pragma unroll 8
    for (int k = 0; k < DIM; ++k) {
        float hv[4], wv[4], uv[4];
        #pragma unroll
        for (int r = 0; r < 4; ++r) hv[r] = hs[rb + r][k];
        #pragma unroll
        for (int c = 0; c < 4; ++c) { wv[c] = Ws[cb + c][k]; uv[c] = Us[cb + c][k]; }
        #pragma unroll
        for (int r = 0; r < 4; ++r)
            #pragma unroll
            for (int c = 0; c < 4; ++c) {
                accz[r][c] += hv[r] * wv[c];
                accu[r][c] += hv[r] * uv[c];
            }
    }

    float asrc[4], adst[4];
    #pragma unroll
    for (int c = 0; c < 4; ++c) { asrc[c] = A[cb + c]; adst[c] = A[DIM + cb + c]; }

    float ps[4], pd[4];
    #pragma unroll
    for (int r = 0; r < 4; ++r) {
        int n = row0 + rb + r;
        if (n < N_NODES) {
            ushort4 vz, vu;
            vz.x = f2bf(accz[r][0]); vz.y = f2bf(accz[r][1]);
            vz.z = f2bf(accz[r][2]); vz.w = f2bf(accz[r][3]);
            vu.x = f2bf(accu[r][0]); vu.y = f2bf(accu[r][1]);
            vu.z = f2bf(accu[r][2]); vu.w = f2bf(accu[r][3]);
            *(ushort4*)&zb[(size_t)n * DIM + cb]  = vz;
            *(ushort4*)&zib[(size_t)n * DIM + cb] = vu;
        }
        float s = 0.f, t = 0.f;
        #pragma unroll
        for (int c = 0; c < 4; ++c) { s += accz[r][c] * asrc[c]; t += accz[r][c] * adst[c]; }
        ps[r] = s; pd[r] = t;
    }
    #pragma unroll
    for (int m = 1; m < 16; m <<= 1) {
        #pragma unroll
        for (int r = 0; r < 4; ++r) {
            ps[r] += __shfl_xor(ps[r], m, 64);
            pd[r] += __shfl_xor(pd[r], m, 64);
        }
    }
    if ((tid & 15) == 0) {
        #pragma unroll
        for (int r = 0; r < 4; ++r) {
            int n = row0 + rb + r;
            if (n < N_NODES) { s_src[n] = ps[r]; s_dst[n] = pd[r]; }
        }
    }
}

// ============================== partition body ==============================
// Slotted two-pass: LDS histogram -> one global reserve per (block,bucket) ->
// bucket-local sequential writes (the write-back-friendly layout; R13/R14 alternatives lost).
__device__ __forceinline__ void partition_body(
    int vb, const int* __restrict__ src, const int* __restrict__ dst,
    const float* __restrict__ dfeat, int* __restrict__ gcursor,
    int2* __restrict__ part, int* __restrict__ h)
{
    for (int b = threadIdx.x; b < NBUCKET; b += 256) h[b] = 0;
    __syncthreads();
    int base = vb * EPB;
    #pragma unroll
    for (int j = 0; j < EPB / 256; ++j) {
        int e = base + j * 256 + threadIdx.x;
        if (e < N_EDGES) atomicAdd(&h[dst[e] >> NPB_SHIFT], 1);
    }
    __syncthreads();
    // reserve: h[b] becomes this block's global write cursor for bucket b
    for (int b = threadIdx.x; b < NBUCKET; b += 256) {
        int v = h[b];
        h[b] = v ? (b * CAP + atomicAdd(&gcursor[b], v)) : 0;
    }
    __syncthreads();
    #pragma unroll
    for (int j = 0; j < EPB / 256; ++j) {
        int e = base + j * 256 + threadIdx.x;
        if (e < N_EDGES) {
            int d = dst[e];
            int pos = atomicAdd(&h[d >> NPB_SHIFT], 1);
            part[pos] = make_int2(((d & (NPB - 1)) << 16) | src[e], __float_as_int(dfeat[e]));
        }
    }
}

// ============================== K1: nl1 (2/3 of blocks) || partition (1/3) ==============================
struct K1NL { float Ws[DIM][DIM + 1]; float Us[DIM][DIM + 1]; float hs[64][DIM + 1]; };
union K1U { K1NL nl; int hist[NBUCKET]; };

__global__ __launch_bounds__(256) void k1_nl_part(
    const float* __restrict__ h, const float* __restrict__ W0,
    const float* __restrict__ U0, const float* __restrict__ A0,
    ushort* __restrict__ zb, ushort* __restrict__ zib,
    float* __restrict__ ssrc, float* __restrict__ sdst,
    const int* __restrict__ src, const int* __restrict__ dst,
    const float* __restrict__ dd, int* __restrict__ gcursor, int2* __restrict__ part)
{
    __shared__ K1U sm;
    int bid = blockIdx.x;               // 1173 = 3*391 blocks
    int m = bid % 3;
    if (m == 2)
        partition_body(bid / 3, src, dst, dd, gcursor, part, sm.hist);
    else
        nl_body<false>((bid / 3) * 2 + m, h, W0, U0, A0, zb, zib, ssrc, sdst,
                       sm.nl.Ws, sm.nl.Us, sm.nl.hs);
}

// standalone layer-2 GEMM
__global__ __launch_bounds__(256) void node_linear2(
    const ushort* __restrict__ h1b, const float* __restrict__ W,
    const float* __restrict__ U, const float* __restrict__ A,
    ushort* __restrict__ zb, ushort* __restrict__ zib,
    float* __restrict__ ssrc, float* __restrict__ sdst)
{
    __shared__ K1NL sm;
    nl_body<true>(blockIdx.x, h1b, W, U, A, zb, zib, ssrc, sdst, sm.Ws, sm.Us, sm.hs);
}

// ============================== bucket sort ==============================
// one block per bucket: counting sort by local dst; emit edata=(src<<16)|bf16(dval), rowse
__global__ __launch_bounds__(256) void bucket_sort(
    const int2* __restrict__ part, const int* __restrict__ gcursor,
    unsigned* __restrict__ edata, int2* __restrict__ rowse)
{
    __shared__ int cnt[NPB];
    __shared__ int cur[NPB];
    int b = blockIdx.x, t = threadIdx.x;
    int beg = b * CAP, end = beg + gcursor[b];
    if (t < NPB) cnt[t] = 0;
    __syncthreads();
    for (int i = beg + t; i < end; i += 256) atomicAdd(&cnt[part[i].x >> 16], 1);
    __syncthreads();
    if (t < NPB) cur[t] = cnt[t];
    __syncthreads();
    for (int off = 1; off < NPB; off <<= 1) {
        int a = (t < NPB && t >= off) ? cur[t - off] : 0;
        __syncthreads();
        if (t < NPB) cur[t] += a;
        __syncthreads();
    }
    if (t < NPB) {
        int n = (b << NPB_SHIFT) + t;
        int cv = cnt[t];
        int st = beg + cur[t] - cv;
        if (n < N_NODES) rowse[n] = make_int2(st, st + cv);
        cur[t] = st;
    }
    __syncthreads();
    for (int i = beg + t; i < end; i += 256) {
        int2 ed = part[i];
        int loc = ed.x >> 16;
        int pos = atomicAdd(&cur[loc], 1);
        edata[pos] = ((unsigned)(ed.x & 0xFFFF) << 16) | (unsigned)f2bf(__int_as_float(ed.y));
    }
}

// ============================== fused GAT ==============================
// GROUP-PER-NODE (16 lanes/node); packed (src<<16|bf16(ex)) single broadcast; 8-deep gather.
template<bool OUT_BF16>
__global__ __launch_bounds__(256) void gat_fused(
    const int2* __restrict__ rowse, const unsigned* __restrict__ edata,
    const float* __restrict__ s_src, const float* __restrict__ s_dst,
    const ushort* __restrict__ zb, const ushort* __restrict__ zib,
    const float* __restrict__ V, const float* __restrict__ A,
    void* __restrict__ out)
{
    const int n = blockIdx.x * 16 + (threadIdx.x >> 4);   // 50000 = 16*3125, no tail
    const int q = threadIdx.x & 15;
    const int gbase = threadIdx.x & 48;

    int2 se = rowse[n];
    int beg = se.x, end = se.y;
    if (beg == end) {
        if (OUT_BF16) {
            ushort4 zz; zz.x = zz.y = zz.z = zz.w = 0;
            ((ushort4*)out)[(size_t)n * 16 + q] = zz;
        } else {
            ((float4*)out)[(size_t)n * 16 + q] = make_float4(0.f, 0.f, 0.f, 0.f);
        }
        return;
    }

    float vae = V[0] * A[2 * DIM];
    float sd = s_dst[n];

    float l = 0.f;
    float4 a0 = make_float4(0.f, 0.f, 0.f, 0.f);
    float4 a1 = make_float4(0.f, 0.f, 0.f, 0.f);

    for (int c0 = beg; c0 < end; c0 += 16) {
        int c = c0 + q;
        bool valid = c < end;
        unsigned w = valid ? edata[c] : 0u;
        int s = (int)(w >> 16);
        float dv = bf2f((ushort)(w & 0xFFFFu));
        float e = s_src[s] + sd + dv * vae;
        e = (e >= 0.f) ? e : 0.01f * e;
        float ex = valid ? __expf(e) : 0.f;

        float cs = ex;
        #pragma unroll
        for (int off = 8; off >= 1; off >>= 1) cs += __shfl_xor(cs, off, 16);
        l += cs;

        unsigned w2 = valid ? (((unsigned)s << 16) | (unsigned)f2bf(ex)) : 0u;

        int cnt = min(16, end - c0);
        for (int k = 0; k < cnt; k += 8) {
            unsigned wsj[8];
            ushort4 v[8];
            #pragma unroll
            for (int j = 0; j < 8; ++j) {
                wsj[j] = __shfl(w2, gbase + k + j, 64);
                v[j] = *(const ushort4*)&zb[((size_t)(wsj[j] >> 16) << 6) + (q << 2)];
            }
            #pragma unroll
            for (int j = 0; j < 8; ++j) {
                float ej = bf2f((ushort)(wsj[j] & 0xFFFFu));
                if (j & 1) {
                    a1.x += ej * bf2f(v[j].x); a1.y += ej * bf2f(v[j].y);
                    a1.z += ej * bf2f(v[j].z); a1.w += ej * bf2f(v[j].w);
                } else {
                    a0.x += ej * bf2f(v[j].x); a0.y += ej * bf2f(v[j].y);
                    a0.z += ej * bf2f(v[j].z); a0.w += ej * bf2f(v[j].w);
                }
            }
        }
    }
    float inv = 1.f / l;
    ushort4 zu = ((const ushort4*)zib)[(size_t)n * 16 + q];
    float4 o;
    o.x = fmaxf(bf2f(zu.x) + (a0.x + a1.x) * inv, 0.f);
    o.y = fmaxf(bf2f(zu.y) + (a0.y + a1.y) * inv, 0.f);
    o.z = fmaxf(bf2f(zu.z) + (a0.z + a1.z) * inv, 0.f);
    o.w = fmaxf(bf2f(zu.w) + (a0.w + a1.w) * inv, 0.f);
    if (OUT_BF16) {
        ushort4 ob;
        ob.x = f2bf(o.x); ob.y = f2bf(o.y); ob.z = f2bf(o.z); ob.w = f2bf(o.w);
        ((ushort4*)out)[(size_t)n * 16 + q] = ob;
    } else {
        ((float4*)out)[(size_t)n * 16 + q] = o;
    }
}

// ============================== driver ==============================
extern "C" void kernel_launch(void* const* d_in, const int* in_sizes, int n_in,
                              void* d_out, int out_size, void* d_ws, size_t ws_size,
                              hipStream_t stream)
{
    const float* h  = (const float*)d_in[0];
    const float* dd = (const float*)d_in[1];
    const int* src  = (const int*)d_in[2];
    const int* dst  = (const int*)d_in[3];
    const float* V0 = (const float*)d_in[4];
    const float* W0 = (const float*)d_in[5];
    const float* U0 = (const float*)d_in[6];
    const float* A0 = (const float*)d_in[7];
    const float* V1 = (const float*)d_in[8];
    const float* W1 = (const float*)d_in[9];
    const float* U1 = (const float*)d_in[10];
    const float* A1 = (const float*)d_in[11];

    const size_t ND = (size_t)N_NODES * DIM;   // 3.2M
    float* ws    = (float*)d_ws;
    ushort* zb   = (ushort*)ws;                     // ND ushort
    ushort* zib  = zb + ND;                         // ND ushort
    ushort* h1b  = zib + ND;                        // ND ushort
    float* ssrc  = ws + (3 * ND) / 2;               // N floats
    float* sdst  = ssrc + N_NODES;                  // N floats
    int2*  rowse = (int2*)(sdst + N_NODES);         // N int2 (8B-aligned offset)
    int2*  part  = rowse + N_NODES;                 // NBUCKET*CAP int2 (8 MB)
    unsigned* edata = (unsigned*)(part + (size_t)NBUCKET * CAP);  // NBUCKET*CAP u32
    int*   gcursor  = (int*)(edata + (size_t)NBUCKET * CAP);      // NBUCKET int
    float* out   = (float*)d_out;

    // zero bucket cursors (1.6 KB), then layer-1 GEMM || edge partition in ONE launch
    hipMemsetAsync(gcursor, 0, NBUCKET * sizeof(int), stream);
    k1_nl_part<<<3 * NBLK, 256, 0, stream>>>(h, W0, U0, A0, zb, zib, ssrc, sdst,
                                             src, dst, dd, gcursor, part);
    bucket_sort<<<NBUCKET, 256, 0, stream>>>(part, gcursor, edata, rowse);
    gat_fused<true><<<NB_GAT, 256, 0, stream>>>(rowse, edata, ssrc, sdst, zb, zib, V0, A0, h1b);
    node_linear2<<<NB_NL, 256, 0, stream>>>(h1b, W1, U1, A1, zb, zib, ssrc, sdst);
    gat_fused<false><<<NB_GAT, 256, 0, stream>>>(rowse, edata, ssrc, sdst, zb, zib, V1, A1, out);
}

// Round 16
// 193.740 us; speedup vs baseline: 1.4160x; 1.0072x over previous
//
#include <hip/hip_runtime.h>
#include <math.h>

#define N_NODES 50000
#define N_EDGES 800000
#define DIM 64
#define NPB 128
#define NPB_SHIFT 7
#define NBUCKET 391          // ceil(50000/128)
#define CAP 2560             // slot capacity per bucket (mean 2048, sd ~45 -> 11 sigma)
#define EPB 2048             // edges per partition vblock
#define NBLK 391             // ceil(800000/2048)
#define NB_NL 782            // ceil(50000/64)
#define NB_GAT 3125          // 50000/16
#define BPAD 6               // bf16 LDS row pad: 70 ushorts = 35 words (2-way max, free)

// ---- bf16 helpers (RNE) ----
__device__ __forceinline__ ushort f2bf(float x) {
    unsigned b = __float_as_uint(x);
    return (ushort)((b + 0x7FFFu + ((b >> 16) & 1u)) >> 16);
}
__device__ __forceinline__ float bf2f(ushort u) {
    return __uint_as_float(((unsigned)u) << 16);
}

// ============================== node GEMM body (layer 1) ==============================
// fp32 LDS staging, +1 pad (conflict-free). zb = bf16(h @ W^T), zib = bf16(h @ U^T),
// s_src/s_dst = attention projections of z.
__device__ __forceinline__ void nl_body1(
    int vb, const float* __restrict__ hin, const float* __restrict__ W,
    const float* __restrict__ U, const float* __restrict__ A,
    ushort* __restrict__ zb, ushort* __restrict__ zib,
    float* __restrict__ s_src, float* __restrict__ s_dst,
    float (*Ws)[DIM + 1], float (*Us)[DIM + 1], float (*hs)[DIM + 1])
{
    const int tid = threadIdx.x;
    const int row0 = vb * 64;

    for (int i = tid; i < 1024; i += 256) {
        int r = i >> 4, c = (i & 15) * 4;
        float4 w4 = ((const float4*)W)[i];
        float4 u4 = ((const float4*)U)[i];
        Ws[r][c] = w4.x; Ws[r][c + 1] = w4.y; Ws[r][c + 2] = w4.z; Ws[r][c + 3] = w4.w;
        Us[r][c] = u4.x; Us[r][c + 1] = u4.y; Us[r][c + 2] = u4.z; Us[r][c + 3] = u4.w;
        int n = row0 + r;
        float4 h4 = make_float4(0.f, 0.f, 0.f, 0.f);
        if (n < N_NODES) h4 = ((const float4*)hin)[((size_t)n * DIM + c) >> 2];
        hs[r][c] = h4.x; hs[r][c + 1] = h4.y; hs[r][c + 2] = h4.z; hs[r][c + 3] = h4.w;
    }
    __syncthreads();

    const int rb = (tid >> 4) * 4;
    const int cb = (tid & 15) * 4;

    float accz[4][4] = {{0}}, accu[4][4] = {{0}};
    #pragma unroll 8
    for (int k = 0; k < DIM; ++k) {
        float hv[4], wv[4], uv[4];
        #pragma unroll
        for (int r = 0; r < 4; ++r) hv[r] = hs[rb + r][k];
        #pragma unroll
        for (int c = 0; c < 4; ++c) { wv[c] = Ws[cb + c][k]; uv[c] = Us[cb + c][k]; }
        #pragma unroll
        for (int r = 0; r < 4; ++r)
            #pragma unroll
            for (int c = 0; c < 4; ++c) {
                accz[r][c] += hv[r] * wv[c];
                accu[r][c] += hv[r] * uv[c];
            }
    }

    float asrc[4], adst[4];
    #pragma unroll
    for (int c = 0; c < 4; ++c) { asrc[c] = A[cb + c]; adst[c] = A[DIM + cb + c]; }

    float ps[4], pd[4];
    #pragma unroll
    for (int r = 0; r < 4; ++r) {
        int n = row0 + rb + r;
        if (n < N_NODES) {
            ushort4 vz, vu;
            vz.x = f2bf(accz[r][0]); vz.y = f2bf(accz[r][1]);
            vz.z = f2bf(accz[r][2]); vz.w = f2bf(accz[r][3]);
            vu.x = f2bf(accu[r][0]); vu.y = f2bf(accu[r][1]);
            vu.z = f2bf(accu[r][2]); vu.w = f2bf(accu[r][3]);
            *(ushort4*)&zb[(size_t)n * DIM + cb]  = vz;
            *(ushort4*)&zib[(size_t)n * DIM + cb] = vu;
        }
        float s = 0.f, t = 0.f;
        #pragma unroll
        for (int c = 0; c < 4; ++c) { s += accz[r][c] * asrc[c]; t += accz[r][c] * adst[c]; }
        ps[r] = s; pd[r] = t;
    }
    #pragma unroll
    for (int m = 1; m < 16; m <<= 1) {
        #pragma unroll
        for (int r = 0; r < 4; ++r) {
            ps[r] += __shfl_xor(ps[r], m, 64);
            pd[r] += __shfl_xor(pd[r], m, 64);
        }
    }
    if ((tid & 15) == 0) {
        #pragma unroll
        for (int r = 0; r < 4; ++r) {
            int n = row0 + rb + r;
            if (n < N_NODES) { s_src[n] = ps[r]; s_dst[n] = pd[r]; }
        }
    }
}

// ============================== partition body ==============================
// Slotted two-pass: LDS histogram -> one global reserve per (block,bucket) ->
// bucket-local sequential writes.
__device__ __forceinline__ void partition_body(
    int vb, const int* __restrict__ src, const int* __restrict__ dst,
    const float* __restrict__ dfeat, int* __restrict__ gcursor,
    int2* __restrict__ part, int* __restrict__ h)
{
    for (int b = threadIdx.x; b < NBUCKET; b += 256) h[b] = 0;
    __syncthreads();
    int base = vb * EPB;
    #pragma unroll
    for (int j = 0; j < EPB / 256; ++j) {
        int e = base + j * 256 + threadIdx.x;
        if (e < N_EDGES) atomicAdd(&h[dst[e] >> NPB_SHIFT], 1);
    }
    __syncthreads();
    for (int b = threadIdx.x; b < NBUCKET; b += 256) {
        int v = h[b];
        h[b] = v ? (b * CAP + atomicAdd(&gcursor[b], v)) : 0;
    }
    __syncthreads();
    #pragma unroll
    for (int j = 0; j < EPB / 256; ++j) {
        int e = base + j * 256 + threadIdx.x;
        if (e < N_EDGES) {
            int d = dst[e];
            int pos = atomicAdd(&h[d >> NPB_SHIFT], 1);
            part[pos] = make_int2(((d & (NPB - 1)) << 16) | src[e], __float_as_int(dfeat[e]));
        }
    }
}

// ============================== K1: nl1 (2/3) || partition (1/3) ==============================
struct K1NL { float Ws[DIM][DIM + 1]; float Us[DIM][DIM + 1]; float hs[64][DIM + 1]; };
union K1U { K1NL nl; int hist[NBUCKET]; };

__global__ __launch_bounds__(256) void k1_nl_part(
    const float* __restrict__ h, const float* __restrict__ W0,
    const float* __restrict__ U0, const float* __restrict__ A0,
    ushort* __restrict__ zb, ushort* __restrict__ zib,
    float* __restrict__ ssrc, float* __restrict__ sdst,
    const int* __restrict__ src, const int* __restrict__ dst,
    const float* __restrict__ dd, int* __restrict__ gcursor, int2* __restrict__ part)
{
    __shared__ K1U sm;
    int bid = blockIdx.x;               // 1173 = 3*391
    int m = bid % 3;
    if (m == 2)
        partition_body(bid / 3, src, dst, dd, gcursor, part, sm.hist);
    else
        nl_body1((bid / 3) * 2 + m, h, W0, U0, A0, zb, zib, ssrc, sdst,
                 sm.nl.Ws, sm.nl.Us, sm.nl.hs);
}

// ============================== K2: sort + gat1 + nl2 (block = bucket) ==============================
struct K2Srt { int cnt[NPB]; int cur[NPB]; unsigned esh[CAP]; };
struct K2WU  { ushort Ws[DIM][DIM + BPAD]; ushort Us[DIM][DIM + BPAD]; };
union K2U { K2Srt srt; K2WU wu; };

__global__ __launch_bounds__(256) void k2_sort_gat_nl(
    const int2* __restrict__ part, const int* __restrict__ gcursor,
    unsigned* __restrict__ edata, int2* __restrict__ rowse,
    const float* __restrict__ ssrc1, const float* __restrict__ sdst1,
    const ushort* __restrict__ zb1, const ushort* __restrict__ zib1,
    const float* __restrict__ V0, const float* __restrict__ A0,
    const float* __restrict__ W1, const float* __restrict__ U1, const float* __restrict__ A1,
    ushort* __restrict__ zb2, ushort* __restrict__ zib2,
    float* __restrict__ ssrc2, float* __restrict__ sdst2)
{
    __shared__ K2U u;
    __shared__ ushort h1t[NPB][DIM + BPAD];   // bucket's h1 tile (bf16)

    const int b = blockIdx.x, t = threadIdx.x;
    const int n0 = b << NPB_SHIFT;
    const int beg = b * CAP;
    const int cntE = gcursor[b];
    const int end = beg + cntE;

    // ---- phase 1: counting sort of bucket into LDS esh + global edata ----
    if (t < NPB) u.srt.cnt[t] = 0;
    __syncthreads();
    for (int i = beg + t; i < end; i += 256) atomicAdd(&u.srt.cnt[part[i].x >> 16], 1);
    __syncthreads();
    int cv = 0;
    if (t < NPB) { cv = u.srt.cnt[t]; u.srt.cur[t] = cv; }
    __syncthreads();
    for (int off = 1; off < NPB; off <<= 1) {
        int a = (t < NPB && t >= off) ? u.srt.cur[t - off] : 0;
        __syncthreads();
        if (t < NPB) u.srt.cur[t] += a;
        __syncthreads();
    }
    if (t < NPB) {
        int n = n0 + t;
        int stl = u.srt.cur[t] - cv;
        if (n < N_NODES) rowse[n] = make_int2(beg + stl, beg + stl + cv);
        u.srt.cur[t] = stl;
    }
    __syncthreads();
    for (int i = beg + t; i < end; i += 256) {
        int2 ed = part[i];
        int loc = ed.x >> 16;
        int pos = atomicAdd(&u.srt.cur[loc], 1);
        unsigned pk = ((unsigned)(ed.x & 0xFFFF) << 16) | (unsigned)f2bf(__int_as_float(ed.y));
        u.srt.esh[pos] = pk;
        edata[beg + pos] = pk;
    }
    __syncthreads();   // cur[t] = local end, cnt[t] = count

    // ---- phase 2: GAT for the bucket's 128 nodes; h1 -> LDS tile ----
    {
        const float vae = V0[0] * A0[2 * DIM];
        const int gid = t >> 4, q = t & 15, gbase = t & 48;
        for (int p = 0; p < 8; ++p) {
            int tn = p * 16 + gid;
            int n = n0 + tn;
            if (n >= N_NODES) continue;
            int endl = u.srt.cur[tn];
            int stl  = endl - u.srt.cnt[tn];
            if (stl == endl) {
                ushort4 zz; zz.x = zz.y = zz.z = zz.w = 0;
                *(ushort4*)&h1t[tn][q << 2] = zz;
                continue;
            }
            float sd = sdst1[n];
            float l = 0.f;
            float4 a0v = make_float4(0.f, 0.f, 0.f, 0.f);
            float4 a1v = make_float4(0.f, 0.f, 0.f, 0.f);
            for (int c0 = stl; c0 < endl; c0 += 16) {
                int c = c0 + q;
                bool valid = c < endl;
                unsigned w = valid ? u.srt.esh[c] : 0u;
                int s = (int)(w >> 16);
                float dv = bf2f((ushort)(w & 0xFFFFu));
                float e = ssrc1[s] + sd + dv * vae;
                e = (e >= 0.f) ? e : 0.01f * e;
                float ex = valid ? __expf(e) : 0.f;

                float cs = ex;
                #pragma unroll
                for (int off = 8; off >= 1; off >>= 1) cs += __shfl_xor(cs, off, 16);
                l += cs;

                unsigned w2 = valid ? (((unsigned)s << 16) | (unsigned)f2bf(ex)) : 0u;
                int cnt = min(16, endl - c0);
                for (int k = 0; k < cnt; k += 8) {
                    unsigned wsj[8];
                    ushort4 v[8];
                    #pragma unroll
                    for (int j = 0; j < 8; ++j) {
                        wsj[j] = __shfl(w2, gbase + k + j, 64);
                        v[j] = *(const ushort4*)&zb1[((size_t)(wsj[j] >> 16) << 6) + (q << 2)];
                    }
                    #pragma unroll
                    for (int j = 0; j < 8; ++j) {
                        float ej = bf2f((ushort)(wsj[j] & 0xFFFFu));
                        if (j & 1) {
                            a1v.x += ej * bf2f(v[j].x); a1v.y += ej * bf2f(v[j].y);
                            a1v.z += ej * bf2f(v[j].z); a1v.w += ej * bf2f(v[j].w);
                        } else {
                            a0v.x += ej * bf2f(v[j].x); a0v.y += ej * bf2f(v[j].y);
                            a0v.z += ej * bf2f(v[j].z); a0v.w += ej * bf2f(v[j].w);
                        }
                    }
                }
            }
            float inv = 1.f / l;
            ushort4 zu = *(const ushort4*)&zib1[((size_t)n << 6) + (q << 2)];
            ushort4 ob;
            ob.x = f2bf(fmaxf(bf2f(zu.x) + (a0v.x + a1v.x) * inv, 0.f));
            ob.y = f2bf(fmaxf(bf2f(zu.y) + (a0v.y + a1v.y) * inv, 0.f));
            ob.z = f2bf(fmaxf(bf2f(zu.z) + (a0v.z + a1v.z) * inv, 0.f));
            ob.w = f2bf(fmaxf(bf2f(zu.w) + (a0v.w + a1v.w) * inv, 0.f));
            *(ushort4*)&h1t[tn][q << 2] = ob;
        }
    }
    __syncthreads();

    // ---- phase 3: layer-2 node GEMM on the h1 tile (W1/U1 staged bf16) ----
    for (int i = t; i < 1024; i += 256) {
        int r = i >> 4, c = (i & 15) * 4;
        float4 w4 = ((const float4*)W1)[i];
        float4 u4 = ((const float4*)U1)[i];
        ushort4 wp, up;
        wp.x = f2bf(w4.x); wp.y = f2bf(w4.y); wp.z = f2bf(w4.z); wp.w = f2bf(w4.w);
        up.x = f2bf(u4.x); up.y = f2bf(u4.y); up.z = f2bf(u4.z); up.w = f2bf(u4.w);
        *(ushort4*)&u.wu.Ws[r][c] = wp;
        *(ushort4*)&u.wu.Us[r][c] = up;
    }
    __syncthreads();

    const int rb = (t >> 4) * 4;
    const int cb = (t & 15) * 4;
    float asrc[4], adst[4];
    #pragma unroll
    for (int c = 0; c < 4; ++c) { asrc[c] = A1[cb + c]; adst[c] = A1[DIM + cb + c]; }

    for (int half = 0; half < 2; ++half) {
        const int rowb = half * 64;
        float accz[4][4] = {{0}}, accu[4][4] = {{0}};
        #pragma unroll 4
        for (int k = 0; k < DIM; k += 4) {
            float hv[4][4], wv[4][4], uv[4][4];
            #pragma unroll
            for (int r = 0; r < 4; ++r) {
                ushort4 hb = *(const ushort4*)&h1t[rowb + rb + r][k];
                hv[r][0] = bf2f(hb.x); hv[r][1] = bf2f(hb.y);
                hv[r][2] = bf2f(hb.z); hv[r][3] = bf2f(hb.w);
            }
            #pragma unroll
            for (int c = 0; c < 4; ++c) {
                ushort4 wb = *(const ushort4*)&u.wu.Ws[cb + c][k];
                ushort4 ub = *(const ushort4*)&u.wu.Us[cb + c][k];
                wv[c][0] = bf2f(wb.x); wv[c][1] = bf2f(wb.y);
                wv[c][2] = bf2f(wb.z); wv[c][3] = bf2f(wb.w);
                uv[c][0] = bf2f(ub.x); uv[c][1] = bf2f(ub.y);
                uv[c][2] = bf2f(ub.z); uv[c][3] = bf2f(ub.w);
            }
            #pragma unroll
            for (int r = 0; r < 4; ++r)
                #pragma unroll
                for (int c = 0; c < 4; ++c) {
                    accz[r][c] += hv[r][0] * wv[c][0] + hv[r][1] * wv[c][1]
                                + hv[r][2] * wv[c][2] + hv[r][3] * wv[c][3];
                    accu[r][c] += hv[r][0] * uv[c][0] + hv[r][1] * uv[c][1]
                                + hv[r][2] * uv[c][2] + hv[r][3] * uv[c][3];
                }
        }
        float ps[4], pd[4];
        #pragma unroll
        for (int r = 0; r < 4; ++r) {
            int n = n0 + rowb + rb + r;
            if (n < N_NODES) {
                ushort4 vz, vu;
                vz.x = f2bf(accz[r][0]); vz.y = f2bf(accz[r][1]);
                vz.z = f2bf(accz[r][2]); vz.w = f2bf(accz[r][3]);
                vu.x = f2bf(accu[r][0]); vu.y = f2bf(accu[r][1]);
                vu.z = f2bf(accu[r][2]); vu.w = f2bf(accu[r][3]);
                *(ushort4*)&zb2[(size_t)n * DIM + cb]  = vz;
                *(ushort4*)&zib2[(size_t)n * DIM + cb] = vu;
            }
            float s = 0.f, tt = 0.f;
            #pragma unroll
            for (int c = 0; c < 4; ++c) { s += accz[r][c] * asrc[c]; tt += accz[r][c] * adst[c]; }
            ps[r] = s; pd[r] = tt;
        }
        #pragma unroll
        for (int m = 1; m < 16; m <<= 1) {
            #pragma unroll
            for (int r = 0; r < 4; ++r) {
                ps[r] += __shfl_xor(ps[r], m, 64);
                pd[r] += __shfl_xor(pd[r], m, 64);
            }
        }
        if ((t & 15) == 0) {
            #pragma unroll
            for (int r = 0; r < 4; ++r) {
                int n = n0 + rowb + rb + r;
                if (n < N_NODES) { ssrc2[n] = ps[r]; sdst2[n] = pd[r]; }
            }
        }
    }
}

// ============================== fused GAT (layer 2) ==============================
__global__ __launch_bounds__(256) void gat_fused2(
    const int2* __restrict__ rowse, const unsigned* __restrict__ edata,
    const float* __restrict__ s_src, const float* __restrict__ s_dst,
    const ushort* __restrict__ zb, const ushort* __restrict__ zib,
    const float* __restrict__ V, const float* __restrict__ A,
    float* __restrict__ out)
{
    const int n = blockIdx.x * 16 + (threadIdx.x >> 4);   // 50000 = 16*3125
    const int q = threadIdx.x & 15;
    const int gbase = threadIdx.x & 48;

    int2 se = rowse[n];
    int beg = se.x, end = se.y;
    if (beg == end) {
        ((float4*)out)[(size_t)n * 16 + q] = make_float4(0.f, 0.f, 0.f, 0.f);
        return;
    }

    float vae = V[0] * A[2 * DIM];
    float sd = s_dst[n];

    float l = 0.f;
    float4 a0 = make_float4(0.f, 0.f, 0.f, 0.f);
    float4 a1 = make_float4(0.f, 0.f, 0.f, 0.f);

    for (int c0 = beg; c0 < end; c0 += 16) {
        int c = c0 + q;
        bool valid = c < end;
        unsigned w = valid ? edata[c] : 0u;
        int s = (int)(w >> 16);
        float dv = bf2f((ushort)(w & 0xFFFFu));
        float e = s_src[s] + sd + dv * vae;
        e = (e >= 0.f) ? e : 0.01f * e;
        float ex = valid ? __expf(e) : 0.f;

        float cs = ex;
        #pragma unroll
        for (int off = 8; off >= 1; off >>= 1) cs += __shfl_xor(cs, off, 16);
        l += cs;

        unsigned w2 = valid ? (((unsigned)s << 16) | (unsigned)f2bf(ex)) : 0u;

        int cnt = min(16, end - c0);
        for (int k = 0; k < cnt; k += 8) {
            unsigned wsj[8];
            ushort4 v[8];
            #pragma unroll
            for (int j = 0; j < 8; ++j) {
                wsj[j] = __shfl(w2, gbase + k + j, 64);
                v[j] = *(const ushort4*)&zb[((size_t)(wsj[j] >> 16) << 6) + (q << 2)];
            }
            #pragma unroll
            for (int j = 0; j < 8; ++j) {
                float ej = bf2f((ushort)(wsj[j] & 0xFFFFu));
                if (j & 1) {
                    a1.x += ej * bf2f(v[j].x); a1.y += ej * bf2f(v[j].y);
                    a1.z += ej * bf2f(v[j].z); a1.w += ej * bf2f(v[j].w);
                } else {
                    a0.x += ej * bf2f(v[j].x); a0.y += ej * bf2f(v[j].y);
                    a0.z += ej * bf2f(v[j].z); a0.w += ej * bf2f(v[j].w);
                }
            }
        }
    }
    float inv = 1.f / l;
    ushort4 zu = ((const ushort4*)zib)[(size_t)n * 16 + q];
    float4 o;
    o.x = fmaxf(bf2f(zu.x) + (a0.x + a1.x) * inv, 0.f);
    o.y = fmaxf(bf2f(zu.y) + (a0.y + a1.y) * inv, 0.f);
    o.z = fmaxf(bf2f(zu.z) + (a0.z + a1.z) * inv, 0.f);
    o.w = fmaxf(bf2f(zu.w) + (a0.w + a1.w) * inv, 0.f);
    ((float4*)out)[(size_t)n * 16 + q] = o;
}

// ============================== driver ==============================
extern "C" void kernel_launch(void* const* d_in, const int* in_sizes, int n_in,
                              void* d_out, int out_size, void* d_ws, size_t ws_size,
                              hipStream_t stream)
{
    const float* h  = (const float*)d_in[0];
    const float* dd = (const float*)d_in[1];
    const int* src  = (const int*)d_in[2];
    const int* dst  = (const int*)d_in[3];
    const float* V0 = (const float*)d_in[4];
    const float* W0 = (const float*)d_in[5];
    const float* U0 = (const float*)d_in[6];
    const float* A0 = (const float*)d_in[7];
    const float* V1 = (const float*)d_in[8];
    const float* W1 = (const float*)d_in[9];
    const float* U1 = (const float*)d_in[10];
    const float* A1 = (const float*)d_in[11];

    const size_t ND = (size_t)N_NODES * DIM;   // 3.2M
    float* ws    = (float*)d_ws;
    ushort* zb1  = (ushort*)ws;                     // ND ushort
    ushort* zib1 = zb1 + ND;                        // ND ushort
    ushort* zb2  = zib1 + ND;                       // ND ushort
    ushort* zib2 = zb2 + ND;                        // ND ushort  (4*ND us = 2*ND floats)
    float* ssrc1 = ws + 2 * ND;                     // N floats
    float* sdst1 = ssrc1 + N_NODES;
    float* ssrc2 = sdst1 + N_NODES;
    float* sdst2 = ssrc2 + N_NODES;
    int2*  rowse = (int2*)(sdst2 + N_NODES);        // N int2 (offset even -> 8B aligned)
    int2*  part  = rowse + N_NODES;                 // NBUCKET*CAP int2 (8 MB)
    unsigned* edata = (unsigned*)(part + (size_t)NBUCKET * CAP);  // NBUCKET*CAP u32
    int*   gcursor  = (int*)(edata + (size_t)NBUCKET * CAP);      // NBUCKET int
    float* out   = (float*)d_out;

    // 4 dispatches: memset, k1(nl1||partition), K2(sort+gat1+nl2), gat2
    hipMemsetAsync(gcursor, 0, NBUCKET * sizeof(int), stream);
    k1_nl_part<<<3 * NBLK, 256, 0, stream>>>(h, W0, U0, A0, zb1, zib1, ssrc1, sdst1,
                                             src, dst, dd, gcursor, part);
    k2_sort_gat_nl<<<NBUCKET, 256, 0, stream>>>(part, gcursor, edata, rowse,
                                                ssrc1, sdst1, zb1, zib1, V0, A0,
                                                W1, U1, A1, zb2, zib2, ssrc2, sdst2);
    gat_fused2<<<NB_GAT, 256, 0, stream>>>(rowse, edata, ssrc2, sdst2, zb2, zib2, V1, A1, out);
}

// Round 17
// 181.454 us; speedup vs baseline: 1.5118x; 1.0677x over previous
//
#include <hip/hip_runtime.h>
#include <math.h>

#define N_NODES 50000
#define N_EDGES 800000
#define DIM 64
#define NPB 64
#define NPB_SHIFT 6
#define NBUCKET 782          // ceil(50000/64)
#define CAP 1280             // slot capacity per bucket (mean ~1023, sd ~32 -> 8 sigma)
#define EPB 2048             // edges per partition vblock
#define NBLK 391             // ceil(800000/2048)
#define NB_GAT 3125          // 50000/16
#define BPAD 6               // bf16 LDS row pad: 70 ushorts = 35 words (2-way max, free)

// ---- bf16 helpers (RNE) ----
__device__ __forceinline__ ushort f2bf(float x) {
    unsigned b = __float_as_uint(x);
    return (ushort)((b + 0x7FFFu + ((b >> 16) & 1u)) >> 16);
}
__device__ __forceinline__ float bf2f(ushort u) {
    return __uint_as_float(((unsigned)u) << 16);
}

// ============================== node GEMM body (layer 1) ==============================
// fp32 LDS staging, +1 pad (conflict-free). zb = bf16(h @ W^T), zib = bf16(h @ U^T),
// s_src/s_dst = attention projections of z.
__device__ __forceinline__ void nl_body1(
    int vb, const float* __restrict__ hin, const float* __restrict__ W,
    const float* __restrict__ U, const float* __restrict__ A,
    ushort* __restrict__ zb, ushort* __restrict__ zib,
    float* __restrict__ s_src, float* __restrict__ s_dst,
    float (*Ws)[DIM + 1], float (*Us)[DIM + 1], float (*hs)[DIM + 1])
{
    const int tid = threadIdx.x;
    const int row0 = vb * 64;

    for (int i = tid; i < 1024; i += 256) {
        int r = i >> 4, c = (i & 15) * 4;
        float4 w4 = ((const float4*)W)[i];
        float4 u4 = ((const float4*)U)[i];
        Ws[r][c] = w4.x; Ws[r][c + 1] = w4.y; Ws[r][c + 2] = w4.z; Ws[r][c + 3] = w4.w;
        Us[r][c] = u4.x; Us[r][c + 1] = u4.y; Us[r][c + 2] = u4.z; Us[r][c + 3] = u4.w;
        int n = row0 + r;
        float4 h4 = make_float4(0.f, 0.f, 0.f, 0.f);
        if (n < N_NODES) h4 = ((const float4*)hin)[((size_t)n * DIM + c) >> 2];
        hs[r][c] = h4.x; hs[r][c + 1] = h4.y; hs[r][c + 2] = h4.z; hs[r][c + 3] = h4.w;
    }
    __syncthreads();

    const int rb = (tid >> 4) * 4;
    const int cb = (tid & 15) * 4;

    float accz[4][4] = {{0}}, accu[4][4] = {{0}};
    #pragma unroll 8
    for (int k = 0; k < DIM; ++k) {
        float hv[4], wv[4], uv[4];
        #pragma unroll
        for (int r = 0; r < 4; ++r) hv[r] = hs[rb + r][k];
        #pragma unroll
        for (int c = 0; c < 4; ++c) { wv[c] = Ws[cb + c][k]; uv[c] = Us[cb + c][k]; }
        #pragma unroll
        for (int r = 0; r < 4; ++r)
            #pragma unroll
            for (int c = 0; c < 4; ++c) {
                accz[r][c] += hv[r] * wv[c];
                accu[r][c] += hv[r] * uv[c];
            }
    }

    float asrc[4], adst[4];
    #pragma unroll
    for (int c = 0; c < 4; ++c) { asrc[c] = A[cb + c]; adst[c] = A[DIM + cb + c]; }

    float ps[4], pd[4];
    #pragma unroll
    for (int r = 0; r < 4; ++r) {
        int n = row0 + rb + r;
        if (n < N_NODES) {
            ushort4 vz, vu;
            vz.x = f2bf(accz[r][0]); vz.y = f2bf(accz[r][1]);
            vz.z = f2bf(accz[r][2]); vz.w = f2bf(accz[r][3]);
            vu.x = f2bf(accu[r][0]); vu.y = f2bf(accu[r][1]);
            vu.z = f2bf(accu[r][2]); vu.w = f2bf(accu[r][3]);
            *(ushort4*)&zb[(size_t)n * DIM + cb]  = vz;
            *(ushort4*)&zib[(size_t)n * DIM + cb] = vu;
        }
        float s = 0.f, t = 0.f;
        #pragma unroll
        for (int c = 0; c < 4; ++c) { s += accz[r][c] * asrc[c]; t += accz[r][c] * adst[c]; }
        ps[r] = s; pd[r] = t;
    }
    #pragma unroll
    for (int m = 1; m < 16; m <<= 1) {
        #pragma unroll
        for (int r = 0; r < 4; ++r) {
            ps[r] += __shfl_xor(ps[r], m, 64);
            pd[r] += __shfl_xor(pd[r], m, 64);
        }
    }
    if ((tid & 15) == 0) {
        #pragma unroll
        for (int r = 0; r < 4; ++r) {
            int n = row0 + rb + r;
            if (n < N_NODES) { s_src[n] = ps[r]; s_dst[n] = pd[r]; }
        }
    }
}

// ============================== partition body ==============================
// Slotted two-pass: LDS histogram (782 buckets of 64 nodes) -> one global reserve per
// (block,bucket) -> bucket-local sequential writes.
__device__ __forceinline__ void partition_body(
    int vb, const int* __restrict__ src, const int* __restrict__ dst,
    const float* __restrict__ dfeat, int* __restrict__ gcursor,
    int2* __restrict__ part, int* __restrict__ h)
{
    for (int b = threadIdx.x; b < NBUCKET; b += 256) h[b] = 0;
    __syncthreads();
    int base = vb * EPB;
    #pragma unroll
    for (int j = 0; j < EPB / 256; ++j) {
        int e = base + j * 256 + threadIdx.x;
        if (e < N_EDGES) atomicAdd(&h[dst[e] >> NPB_SHIFT], 1);
    }
    __syncthreads();
    for (int b = threadIdx.x; b < NBUCKET; b += 256) {
        int v = h[b];
        h[b] = v ? (b * CAP + atomicAdd(&gcursor[b], v)) : 0;
    }
    __syncthreads();
    #pragma unroll
    for (int j = 0; j < EPB / 256; ++j) {
        int e = base + j * 256 + threadIdx.x;
        if (e < N_EDGES) {
            int d = dst[e];
            int pos = atomicAdd(&h[d >> NPB_SHIFT], 1);
            part[pos] = make_int2(((d & (NPB - 1)) << 16) | src[e], __float_as_int(dfeat[e]));
        }
    }
}

// ============================== K1: nl1 (2/3) || partition (1/3) ==============================
struct K1NL { float Ws[DIM][DIM + 1]; float Us[DIM][DIM + 1]; float hs[64][DIM + 1]; };
union K1U { K1NL nl; int hist[NBUCKET]; };

__global__ __launch_bounds__(256) void k1_nl_part(
    const float* __restrict__ h, const float* __restrict__ W0,
    const float* __restrict__ U0, const float* __restrict__ A0,
    ushort* __restrict__ zb, ushort* __restrict__ zib,
    float* __restrict__ ssrc, float* __restrict__ sdst,
    const int* __restrict__ src, const int* __restrict__ dst,
    const float* __restrict__ dd, int* __restrict__ gcursor, int2* __restrict__ part)
{
    __shared__ K1U sm;
    int bid = blockIdx.x;               // 1173 = 3*391
    int m = bid % 3;
    if (m == 2)
        partition_body(bid / 3, src, dst, dd, gcursor, part, sm.hist);
    else
        nl_body1((bid / 3) * 2 + m, h, W0, U0, A0, zb, zib, ssrc, sdst,
                 sm.nl.Ws, sm.nl.Us, sm.nl.hs);
}

// ============================== K2: sort + gat1 + nl2 (block = 64-node bucket) ==============================
struct K2Srt { int cnt[NPB]; int cur[NPB]; unsigned esh[CAP]; };
struct K2WU  { ushort Ws[DIM][DIM + BPAD]; ushort Us[DIM][DIM + BPAD]; };
union K2U { K2Srt srt; K2WU wu; };

__global__ __launch_bounds__(256) void k2_sort_gat_nl(
    const int2* __restrict__ part, const int* __restrict__ gcursor,
    unsigned* __restrict__ edata, int2* __restrict__ rowse,
    const float* __restrict__ ssrc1, const float* __restrict__ sdst1,
    const ushort* __restrict__ zb1, const ushort* __restrict__ zib1,
    const float* __restrict__ V0, const float* __restrict__ A0,
    const float* __restrict__ W1, const float* __restrict__ U1, const float* __restrict__ A1,
    ushort* __restrict__ zb2, ushort* __restrict__ zib2,
    float* __restrict__ ssrc2, float* __restrict__ sdst2)
{
    __shared__ K2U u;
    __shared__ ushort h1t[NPB][DIM + BPAD];   // bucket's h1 tile (bf16), 64 rows

    const int b = blockIdx.x, t = threadIdx.x;
    const int n0 = b << NPB_SHIFT;
    const int beg = b * CAP;
    const int cntE = gcursor[b];
    const int end = beg + cntE;

    // ---- phase 1: counting sort of bucket into LDS esh + global edata ----
    if (t < NPB) u.srt.cnt[t] = 0;
    __syncthreads();
    for (int i = beg + t; i < end; i += 256) atomicAdd(&u.srt.cnt[part[i].x >> 16], 1);
    __syncthreads();
    int cv = 0;
    if (t < NPB) { cv = u.srt.cnt[t]; u.srt.cur[t] = cv; }
    __syncthreads();
    for (int off = 1; off < NPB; off <<= 1) {
        int a = (t < NPB && t >= off) ? u.srt.cur[t - off] : 0;
        __syncthreads();
        if (t < NPB) u.srt.cur[t] += a;
        __syncthreads();
    }
    if (t < NPB) {
        int n = n0 + t;
        int stl = u.srt.cur[t] - cv;
        if (n < N_NODES) rowse[n] = make_int2(beg + stl, beg + stl + cv);
        u.srt.cur[t] = stl;
    }
    __syncthreads();
    for (int i = beg + t; i < end; i += 256) {
        int2 ed = part[i];
        int loc = ed.x >> 16;
        int pos = atomicAdd(&u.srt.cur[loc], 1);
        unsigned pk = ((unsigned)(ed.x & 0xFFFF) << 16) | (unsigned)f2bf(__int_as_float(ed.y));
        u.srt.esh[pos] = pk;
        edata[beg + pos] = pk;
    }
    __syncthreads();   // cur[t] = local end, cnt[t] = count

    // ---- phase 2: GAT for the bucket's 64 nodes; h1 -> LDS tile ----
    {
        const float vae = V0[0] * A0[2 * DIM];
        const int gid = t >> 4, q = t & 15, gbase = t & 48;
        for (int p = 0; p < 4; ++p) {
            int tn = p * 16 + gid;
            int n = n0 + tn;
            if (n >= N_NODES) continue;
            int endl = u.srt.cur[tn];
            int stl  = endl - u.srt.cnt[tn];
            if (stl == endl) {
                ushort4 zz; zz.x = zz.y = zz.z = zz.w = 0;
                *(ushort4*)&h1t[tn][q << 2] = zz;
                continue;
            }
            float sd = sdst1[n];
            float l = 0.f;
            float4 a0v = make_float4(0.f, 0.f, 0.f, 0.f);
            float4 a1v = make_float4(0.f, 0.f, 0.f, 0.f);
            for (int c0 = stl; c0 < endl; c0 += 16) {
                int c = c0 + q;
                bool valid = c < endl;
                unsigned w = valid ? u.srt.esh[c] : 0u;
                int s = (int)(w >> 16);
                float dv = bf2f((ushort)(w & 0xFFFFu));
                float e = ssrc1[s] + sd + dv * vae;
                e = (e >= 0.f) ? e : 0.01f * e;
                float ex = valid ? __expf(e) : 0.f;

                float cs = ex;
                #pragma unroll
                for (int off = 8; off >= 1; off >>= 1) cs += __shfl_xor(cs, off, 16);
                l += cs;

                unsigned w2 = valid ? (((unsigned)s << 16) | (unsigned)f2bf(ex)) : 0u;
                int cnt = min(16, endl - c0);
                for (int k = 0; k < cnt; k += 8) {
                    unsigned wsj[8];
                    ushort4 v[8];
                    #pragma unroll
                    for (int j = 0; j < 8; ++j) {
                        wsj[j] = __shfl(w2, gbase + k + j, 64);
                        v[j] = *(const ushort4*)&zb1[((size_t)(wsj[j] >> 16) << 6) + (q << 2)];
                    }
                    #pragma unroll
                    for (int j = 0; j < 8; ++j) {
                        float ej = bf2f((ushort)(wsj[j] & 0xFFFFu));
                        if (j & 1) {
                            a1v.x += ej * bf2f(v[j].x); a1v.y += ej * bf2f(v[j].y);
                            a1v.z += ej * bf2f(v[j].z); a1v.w += ej * bf2f(v[j].w);
                        } else {
                            a0v.x += ej * bf2f(v[j].x); a0v.y += ej * bf2f(v[j].y);
                            a0v.z += ej * bf2f(v[j].z); a0v.w += ej * bf2f(v[j].w);
                        }
                    }
                }
            }
            float inv = 1.f / l;
            ushort4 zu = *(const ushort4*)&zib1[((size_t)n << 6) + (q << 2)];
            ushort4 ob;
            ob.x = f2bf(fmaxf(bf2f(zu.x) + (a0v.x + a1v.x) * inv, 0.f));
            ob.y = f2bf(fmaxf(bf2f(zu.y) + (a0v.y + a1v.y) * inv, 0.f));
            ob.z = f2bf(fmaxf(bf2f(zu.z) + (a0v.z + a1v.z) * inv, 0.f));
            ob.w = f2bf(fmaxf(bf2f(zu.w) + (a0v.w + a1v.w) * inv, 0.f));
            *(ushort4*)&h1t[tn][q << 2] = ob;
        }
    }
    __syncthreads();

    // ---- phase 3: layer-2 node GEMM on the 64-row h1 tile (W1/U1 staged bf16) ----
    for (int i = t; i < 1024; i += 256) {
        int r = i >> 4, c = (i & 15) * 4;
        float4 w4 = ((const float4*)W1)[i];
        float4 u4 = ((const float4*)U1)[i];
        ushort4 wp, up;
        wp.x = f2bf(w4.x); wp.y = f2bf(w4.y); wp.z = f2bf(w4.z); wp.w = f2bf(w4.w);
        up.x = f2bf(u4.x); up.y = f2bf(u4.y); up.z = f2bf(u4.z); up.w = f2bf(u4.w);
        *(ushort4*)&u.wu.Ws[r][c] = wp;
        *(ushort4*)&u.wu.Us[r][c] = up;
    }
    __syncthreads();

    const int rb = (t >> 4) * 4;
    const int cb = (t & 15) * 4;
    float asrc[4], adst[4];
    #pragma unroll
    for (int c = 0; c < 4; ++c) { asrc[c] = A1[cb + c]; adst[c] = A1[DIM + cb + c]; }

    float accz[4][4] = {{0}}, accu[4][4] = {{0}};
    #pragma unroll 4
    for (int k = 0; k < DIM; k += 4) {
        float hv[4][4], wv[4][4], uv[4][4];
        #pragma unroll
        for (int r = 0; r < 4; ++r) {
            ushort4 hb = *(const ushort4*)&h1t[rb + r][k];
            hv[r][0] = bf2f(hb.x); hv[r][1] = bf2f(hb.y);
            hv[r][2] = bf2f(hb.z); hv[r][3] = bf2f(hb.w);
        }
        #pragma unroll
        for (int c = 0; c < 4; ++c) {
            ushort4 wb = *(const ushort4*)&u.wu.Ws[cb + c][k];
            ushort4 ub = *(const ushort4*)&u.wu.Us[cb + c][k];
            wv[c][0] = bf2f(wb.x); wv[c][1] = bf2f(wb.y);
            wv[c][2] = bf2f(wb.z); wv[c][3] = bf2f(wb.w);
            uv[c][0] = bf2f(ub.x); uv[c][1] = bf2f(ub.y);
            uv[c][2] = bf2f(ub.z); uv[c][3] = bf2f(ub.w);
        }
        #pragma unroll
        for (int r = 0; r < 4; ++r)
            #pragma unroll
            for (int c = 0; c < 4; ++c) {
                accz[r][c] += hv[r][0] * wv[c][0] + hv[r][1] * wv[c][1]
                            + hv[r][2] * wv[c][2] + hv[r][3] * wv[c][3];
                accu[r][c] += hv[r][0] * uv[c][0] + hv[r][1] * uv[c][1]
                            + hv[r][2] * uv[c][2] + hv[r][3] * uv[c][3];
            }
    }
    float ps[4], pd[4];
    #pragma unroll
    for (int r = 0; r < 4; ++r) {
        int n = n0 + rb + r;
        if (n < N_NODES) {
            ushort4 vz, vu;
            vz.x = f2bf(accz[r][0]); vz.y = f2bf(accz[r][1]);
            vz.z = f2bf(accz[r][2]); vz.w = f2bf(accz[r][3]);
            vu.x = f2bf(accu[r][0]); vu.y = f2bf(accu[r][1]);
            vu.z = f2bf(accu[r][2]); vu.w = f2bf(accu[r][3]);
            *(ushort4*)&zb2[(size_t)n * DIM + cb]  = vz;
            *(ushort4*)&zib2[(size_t)n * DIM + cb] = vu;
        }
        float s = 0.f, tt = 0.f;
        #pragma unroll
        for (int c = 0; c < 4; ++c) { s += accz[r][c] * asrc[c]; tt += accz[r][c] * adst[c]; }
        ps[r] = s; pd[r] = tt;
    }
    #pragma unroll
    for (int m = 1; m < 16; m <<= 1) {
        #pragma unroll
        for (int r = 0; r < 4; ++r) {
            ps[r] += __shfl_xor(ps[r], m, 64);
            pd[r] += __shfl_xor(pd[r], m, 64);
        }
    }
    if ((t & 15) == 0) {
        #pragma unroll
        for (int r = 0; r < 4; ++r) {
            int n = n0 + rb + r;
            if (n < N_NODES) { ssrc2[n] = ps[r]; sdst2[n] = pd[r]; }
        }
    }
}

// ============================== fused GAT (layer 2) ==============================
__global__ __launch_bounds__(256) void gat_fused2(
    const int2* __restrict__ rowse, const unsigned* __restrict__ edata,
    const float* __restrict__ s_src, const float* __restrict__ s_dst,
    const ushort* __restrict__ zb, const ushort* __restrict__ zib,
    const float* __restrict__ V, const float* __restrict__ A,
    float* __restrict__ out)
{
    const int n = blockIdx.x * 16 + (threadIdx.x >> 4);   // 50000 = 16*3125
    const int q = threadIdx.x & 15;
    const int gbase = threadIdx.x & 48;

    int2 se = rowse[n];
    int beg = se.x, end = se.y;
    if (beg == end) {
        ((float4*)out)[(size_t)n * 16 + q] = make_float4(0.f, 0.f, 0.f, 0.f);
        return;
    }

    float vae = V[0] * A[2 * DIM];
    float sd = s_dst[n];

    float l = 0.f;
    float4 a0 = make_float4(0.f, 0.f, 0.f, 0.f);
    float4 a1 = make_float4(0.f, 0.f, 0.f, 0.f);

    for (int c0 = beg; c0 < end; c0 += 16) {
        int c = c0 + q;
        bool valid = c < end;
        unsigned w = valid ? edata[c] : 0u;
        int s = (int)(w >> 16);
        float dv = bf2f((ushort)(w & 0xFFFFu));
        float e = s_src[s] + sd + dv * vae;
        e = (e >= 0.f) ? e : 0.01f * e;
        float ex = valid ? __expf(e) : 0.f;

        float cs = ex;
        #pragma unroll
        for (int off = 8; off >= 1; off >>= 1) cs += __shfl_xor(cs, off, 16);
        l += cs;

        unsigned w2 = valid ? (((unsigned)s << 16) | (unsigned)f2bf(ex)) : 0u;

        int cnt = min(16, end - c0);
        for (int k = 0; k < cnt; k += 8) {
            unsigned wsj[8];
            ushort4 v[8];
            #pragma unroll
            for (int j = 0; j < 8; ++j) {
                wsj[j] = __shfl(w2, gbase + k + j, 64);
                v[j] = *(const ushort4*)&zb[((size_t)(wsj[j] >> 16) << 6) + (q << 2)];
            }
            #pragma unroll
            for (int j = 0; j < 8; ++j) {
                float ej = bf2f((ushort)(wsj[j] & 0xFFFFu));
                if (j & 1) {
                    a1.x += ej * bf2f(v[j].x); a1.y += ej * bf2f(v[j].y);
                    a1.z += ej * bf2f(v[j].z); a1.w += ej * bf2f(v[j].w);
                } else {
                    a0.x += ej * bf2f(v[j].x); a0.y += ej * bf2f(v[j].y);
                    a0.z += ej * bf2f(v[j].z); a0.w += ej * bf2f(v[j].w);
                }
            }
        }
    }
    float inv = 1.f / l;
    ushort4 zu = ((const ushort4*)zib)[(size_t)n * 16 + q];
    float4 o;
    o.x = fmaxf(bf2f(zu.x) + (a0.x + a1.x) * inv, 0.f);
    o.y = fmaxf(bf2f(zu.y) + (a0.y + a1.y) * inv, 0.f);
    o.z = fmaxf(bf2f(zu.z) + (a0.z + a1.z) * inv, 0.f);
    o.w = fmaxf(bf2f(zu.w) + (a0.w + a1.w) * inv, 0.f);
    ((float4*)out)[(size_t)n * 16 + q] = o;
}

// ============================== driver ==============================
extern "C" void kernel_launch(void* const* d_in, const int* in_sizes, int n_in,
                              void* d_out, int out_size, void* d_ws, size_t ws_size,
                              hipStream_t stream)
{
    const float* h  = (const float*)d_in[0];
    const float* dd = (const float*)d_in[1];
    const int* src  = (const int*)d_in[2];
    const int* dst  = (const int*)d_in[3];
    const float* V0 = (const float*)d_in[4];
    const float* W0 = (const float*)d_in[5];
    const float* U0 = (const float*)d_in[6];
    const float* A0 = (const float*)d_in[7];
    const float* V1 = (const float*)d_in[8];
    const float* W1 = (const float*)d_in[9];
    const float* U1 = (const float*)d_in[10];
    const float* A1 = (const float*)d_in[11];

    const size_t ND = (size_t)N_NODES * DIM;   // 3.2M
    float* ws    = (float*)d_ws;
    ushort* zb1  = (ushort*)ws;                     // ND ushort
    ushort* zib1 = zb1 + ND;                        // ND ushort
    ushort* zb2  = zib1 + ND;                       // ND ushort
    ushort* zib2 = zb2 + ND;                        // ND ushort  (4*ND us = 2*ND floats)
    float* ssrc1 = ws + 2 * ND;                     // N floats
    float* sdst1 = ssrc1 + N_NODES;
    float* ssrc2 = sdst1 + N_NODES;
    float* sdst2 = ssrc2 + N_NODES;
    int2*  rowse = (int2*)(sdst2 + N_NODES);        // N int2 (offset even -> 8B aligned)
    int2*  part  = rowse + N_NODES;                 // NBUCKET*CAP int2 (8 MB)
    unsigned* edata = (unsigned*)(part + (size_t)NBUCKET * CAP);  // NBUCKET*CAP u32
    int*   gcursor  = (int*)(edata + (size_t)NBUCKET * CAP);      // NBUCKET int
    float* out   = (float*)d_out;

    // 4 dispatches: memset, k1(nl1||partition), K2(sort+gat1+nl2), gat2
    hipMemsetAsync(gcursor, 0, NBUCKET * sizeof(int), stream);
    k1_nl_part<<<3 * NBLK, 256, 0, stream>>>(h, W0, U0, A0, zb1, zib1, ssrc1, sdst1,
                                             src, dst, dd, gcursor, part);
    k2_sort_gat_nl<<<NBUCKET, 256, 0, stream>>>(part, gcursor, edata, rowse,
                                                ssrc1, sdst1, zb1, zib1, V0, A0,
                                                W1, U1, A1, zb2, zib2, ssrc2, sdst2);
    gat_fused2<<<NB_GAT, 256, 0, stream>>>(rowse, edata, ssrc2, sdst2, zb2, zib2, V1, A1, out);
}